// Round 10
// baseline (473.023 us; speedup 1.0000x reference)
//
#include <hip/hip_runtime.h>

// SimpleAttention: B=8, S=2048, H=256
// R10: (a) repack via per-lane dword + __ballot (coalesced 256B/wave, no LDS);
//      (b) attn single K/V buffer 37KB -> 4 blocks/CU, launch_bounds(256,4),
//          nsplit=4 (1024 blocks). Harness d_ws 0xAA fill (~150us) is fixed
//          overhead inside the timed window — not addressable.

#define B_ 8
#define S_ 2048
#define H_ 256

typedef __attribute__((ext_vector_type(8))) short s16x8;   // 8 bf16 MFMA A/B frag
typedef __attribute__((ext_vector_type(4))) float f32x4;   // MFMA C/D frag
typedef __attribute__((ext_vector_type(4))) unsigned short u16x4;
typedef __attribute__((ext_vector_type(8))) unsigned short u16x8;

#if __has_builtin(__builtin_amdgcn_exp2f)
#define EXP2F(x) __builtin_amdgcn_exp2f(x)
#else
#define EXP2F(x) exp2f(x)
#endif
#define L2E 1.4426950408889634f

__device__ __forceinline__ unsigned short f2bf(float f) {
  unsigned int u = __builtin_bit_cast(unsigned int, f);
  u += 0x7fffu + ((u >> 16) & 1u);   // RNE
  return (unsigned short)(u >> 16);
}
__device__ __forceinline__ float bf2f(unsigned short h) {
  unsigned int u = ((unsigned int)h) << 16;
  return __builtin_bit_cast(float, u);
}
__device__ __forceinline__ f32x4 mfma_bf16(s16x8 a, s16x8 b, f32x4 c) {
  return __builtin_amdgcn_mfma_f32_16x16x32_bf16(a, b, c, 0, 0, 0);
}
__device__ __forceinline__ float sel4(const float v[4], int r) {
  float t0 = (r & 1) ? v[1] : v[0];
  float t1 = (r & 1) ? v[3] : v[2];
  return (r & 2) ? t1 : t0;
}
// async global->LDS, 16B/lane; LDS dest = wave-uniform base + lane*16
__device__ __forceinline__ void async16(const unsigned short* g, unsigned short* l) {
  __builtin_amdgcn_global_load_lds(
      (const __attribute__((address_space(1))) unsigned int*)g,
      (__attribute__((address_space(3))) unsigned int*)l, 16, 0, 0);
}

// ---------------------------------------------------------------------------
// Kernel 0: W[h][n] fp32 -> Wt[n][h] bf16. grid (48).
// ---------------------------------------------------------------------------
__global__ __launch_bounds__(256) void wt_kernel(
    const float* __restrict__ Wq, const float* __restrict__ Wk,
    const float* __restrict__ Wv, unsigned short* __restrict__ Wt) {
  __shared__ unsigned short tile[64 * 72];
  int z = blockIdx.x >> 4, x = blockIdx.x & 15;
  const float* W = (z == 0) ? Wq : (z == 1) ? Wk : Wv;
  int n0 = (x & 3) * 64, h0 = (x >> 2) * 64;
  int t = threadIdx.x;
#pragma unroll
  for (int j = 0; j < 4; ++j) {
    int c = j * 256 + t;
    int i = c >> 4, ch = c & 15;
    float4 f = *(const float4*)&W[(h0 + i) * 256 + n0 + ch * 4];
    u16x4 p;
    p[0] = f2bf(f.x); p[1] = f2bf(f.y); p[2] = f2bf(f.z); p[3] = f2bf(f.w);
    *(u16x4*)&tile[i * 72 + ch * 4] = p;
  }
  __syncthreads();
#pragma unroll
  for (int j = 0; j < 2; ++j) {
    int c = j * 256 + t;
    int nr = c >> 3, ch = c & 7;
    u16x8 o;
#pragma unroll
    for (int k = 0; k < 8; ++k) o[k] = tile[(ch * 8 + k) * 72 + nr];
    *(u16x8*)&Wt[z * 65536 + (n0 + nr) * 256 + h0 + ch * 8] = o;
  }
}

// ---------------------------------------------------------------------------
// Kernel 1: fused proj (blocks 0..767) + ballot-repack (blocks 768..8959).
// repack: lane reads ONE int32 (wave = 256B contiguous, coalesced);
// __ballot(x!=0) assembles 64 mask bits; lanes 0..3 store one u16 each.
// ---------------------------------------------------------------------------
__global__ __launch_bounds__(256) void fused_kernel(
    const int* __restrict__ mask, unsigned short* __restrict__ Mb,
    const float* __restrict__ Xq, const float* __restrict__ Xk,
    const float* __restrict__ Xv, const unsigned short* __restrict__ Wt,
    unsigned short* __restrict__ Qb, unsigned short* __restrict__ Kb,
    unsigned short* __restrict__ Vt) {
  __shared__ unsigned short plds[16384];        // 32KB (proj path only)

  int t = threadIdx.x;
  int w = t >> 6, lane = t & 63, quad = lane >> 4, l15 = lane & 15;

  if (blockIdx.x >= 768) {
    // ---- repack path: block covers 4096 int32 (16 output-words x 256)
    size_t base = (size_t)(blockIdx.x - 768) * 4096;
#pragma unroll
    for (int s = 0; s < 16; ++s) {
      int x = mask[base + s * 256 + t];
      unsigned long long bm = __ballot(x != 0);
      if (lane < 4) {
        Mb[(base >> 4) + s * 16 + w * 4 + lane] =
            (unsigned short)(bm >> (16 * lane));
      }
    }
    return;
  }

  // ---- proj path (R8/R9 structure)
  int z = blockIdx.x >> 8;                      // 0..2
  int bx = blockIdx.x & 255;
  const float* X = (z == 0) ? Xq : (z == 1) ? Xk : Xv;
  const unsigned short* Wz = Wt + z * 65536;

  int m0 = bx * 64;
  const float* xrow = X + (size_t)(m0 + w * 16 + l15) * H_;

  f32x4 zero4 = {0.f, 0.f, 0.f, 0.f};
  f32x4 acc[16];
#pragma unroll
  for (int i = 0; i < 16; ++i) acc[i] = zero4;

#pragma unroll
  for (int j = 0; j < 4; ++j) {
    int c = j * 256 + t;
    int n = c >> 2, p = c & 3;
    async16(Wz + n * 256 + ((p ^ ((n >> 1) & 3)) << 3),
            plds + j * 2048 + w * 512);
  }
  float4 a0 = *(const float4*)(xrow + quad * 8);
  float4 a1 = *(const float4*)(xrow + quad * 8 + 4);

  for (int c8 = 0; c8 < 8; ++c8) {
    int cur = c8 & 1;
    unsigned short* Wc = plds + cur * 8192;
    __syncthreads();   // drains buf[cur] asyncs; buf[cur^1] free

    if (c8 < 7) {
      unsigned short* Wn = plds + (cur ^ 1) * 8192;
#pragma unroll
      for (int j = 0; j < 4; ++j) {
        int c = j * 256 + t;
        int n = c >> 2, p = c & 3;
        async16(Wz + n * 256 + (c8 + 1) * 32 + ((p ^ ((n >> 1) & 3)) << 3),
                Wn + j * 2048 + w * 512);
      }
    }
    float4 na0, na1;
    if (c8 < 7) {
      na0 = *(const float4*)(xrow + (c8 + 1) * 32 + quad * 8);
      na1 = *(const float4*)(xrow + (c8 + 1) * 32 + quad * 8 + 4);
    }
    s16x8 af;
    af[0] = (short)f2bf(a0.x); af[1] = (short)f2bf(a0.y);
    af[2] = (short)f2bf(a0.z); af[3] = (short)f2bf(a0.w);
    af[4] = (short)f2bf(a1.x); af[5] = (short)f2bf(a1.y);
    af[6] = (short)f2bf(a1.z); af[7] = (short)f2bf(a1.w);

#pragma unroll
    for (int nf = 0; nf < 16; ++nf) {
      int n = nf * 16 + l15;
      s16x8 bf = *(const s16x8*)&Wc[n * 32 + ((quad ^ ((n >> 1) & 3)) << 3)];
      acc[nf] = mfma_bf16(af, bf, acc[nf]);
    }
    a0 = na0; a1 = na1;
  }
  __syncthreads();   // W bufs free; epilogue tile aliases

  float scale = (z == 0) ? 0.0625f : 1.0f;
  int b = m0 >> 11, s0 = m0 & 2047;
#pragma unroll
  for (int h = 0; h < 2; ++h) {
    if (h) __syncthreads();
    if (z < 2) {
#pragma unroll
      for (int nf2 = 0; nf2 < 8; ++nf2) {
        int n = nf2 * 16 + l15;
#pragma unroll
        for (int r = 0; r < 4; ++r)
          plds[(w * 16 + quad * 4 + r) * 136 + n] = f2bf(acc[h * 8 + nf2][r] * scale);
      }
      __syncthreads();
      unsigned short* Y = (z == 0) ? Qb : Kb;
#pragma unroll
      for (int j = 0; j < 4; ++j) {
        int c = j * 256 + t;
        int mr = c >> 4, ch = c & 15;
        u16x8 o = *(const u16x8*)&plds[mr * 136 + ch * 8];
        *(u16x8*)&Y[(size_t)(m0 + mr) * H_ + h * 128 + ch * 8] = o;
      }
    } else {
#pragma unroll
      for (int nf2 = 0; nf2 < 8; ++nf2) {
        int dl = nf2 * 16 + l15;
#pragma unroll
        for (int r = 0; r < 4; ++r)
          plds[dl * 72 + (w * 16 + quad * 4 + r)] = f2bf(acc[h * 8 + nf2][r]);
      }
      __syncthreads();
#pragma unroll
      for (int j = 0; j < 4; ++j) {
        int c = j * 256 + t;                 // 0..1023
        int dr = c >> 3, ch = c & 7;         // d row 0..127, 8-s chunk
        u16x8 o = *(const u16x8*)&plds[dr * 72 + ch * 8];
        *(u16x8*)&Vt[((size_t)b * H_ + h * 128 + dr) * S_ + s0 + ch * 8] = o;
      }
    }
  }
}

// ---------------------------------------------------------------------------
// Kernel 2: flash attention, no-max softmax, SINGLE K/V buffer (37KB LDS) ->
// 4 blocks/CU. grid (8, 32, nsplit=4) = 1024 blocks. 2 barriers/iter
// (issue asyncs, drain); latency covered by 4-block co-residency; K/V are
// XCD-L2-resident (2MB/batch) after first pass.
// ---------------------------------------------------------------------------
__global__ __launch_bounds__(256, 4) void attn_kernel(
    const unsigned short* __restrict__ Qb, const unsigned short* __restrict__ Kb,
    const unsigned short* __restrict__ Vt, const unsigned int* __restrict__ Mb,
    unsigned short* __restrict__ Op, float* __restrict__ Ml,
    float* __restrict__ out) {
  __shared__ unsigned short lds[18944];   // Ks 8192 | Vs 8192 | Ps 2560 u16
  unsigned short* Ks = lds;               // [32 key][256 d]
  unsigned short* Vs = lds + 8192;        // [256 d][32 key]
  unsigned short* Ps = lds + 16384;       // [wave][16 q][40]

  int t = threadIdx.x;
  int w = t >> 6, lane = t & 63, quad = lane >> 4, l15 = lane & 15;
  int b = blockIdx.x;                     // batch -> XCD affinity
  int q0 = blockIdx.y * 64;
  int split = blockIdx.z, nsplit = gridDim.z;
  int kbeg = (64 * split) / nsplit, kend = (64 * (split + 1)) / nsplit;

  s16x8 qa[8];
  {
    const unsigned short* qp =
        Qb + ((size_t)b * S_ + q0 + w * 16 + l15) * H_ + quad * 8;
#pragma unroll
    for (int c = 0; c < 8; ++c) qa[c] = *(const s16x8*)(qp + 32 * c);
  }

  const unsigned short* Kbb = Kb + (size_t)b * S_ * H_;
  const unsigned short* Vbb = Vt + (size_t)b * H_ * S_;

  int krow = lane >> 5, kch = lane & 31;
  int vrow = lane >> 2, vch = lane & 3;

  f32x4 zero4 = {0.f, 0.f, 0.f, 0.f};
  f32x4 acc[16];
#pragma unroll
  for (int i = 0; i < 16; ++i) acc[i] = zero4;
  float l_r[4] = {0.f, 0.f, 0.f, 0.f};

  const unsigned int* mrow[4];
#pragma unroll
  for (int r = 0; r < 4; ++r)
    mrow[r] = Mb + ((size_t)b * S_ + q0 + w * 16 + quad * 4 + r) * 64;

  unsigned int mw[4];
#pragma unroll
  for (int r = 0; r < 4; ++r) mw[r] = mrow[r][kbeg];

  for (int kt = kbeg; kt < kend; ++kt) {
    int k0 = kt * 32;
    __syncthreads();   // A: all waves done reading Ks/Vs (prev iter)
#pragma unroll
    for (int j = 0; j < 4; ++j) {
      int key = (w * 4 + j) * 2 + krow;
      async16(Kbb + ((size_t)(k0 + key) << 8) + ((kch ^ (key & 7)) << 3),
              Ks + (w * 4 + j) * 512);
      int d = w * 64 + j * 16 + vrow;
      async16(Vbb + ((size_t)d << 11) + k0 + ((vch ^ (d & 3)) << 3),
              Vs + (w * 64 + j * 16) * 32);
    }
    __syncthreads();   // B: drain (covered by 3 co-resident blocks)

    unsigned int mwn[4];
    {
      int ktn = (kt + 1 < kend) ? kt + 1 : kt;
#pragma unroll
      for (int r = 0; r < 4; ++r) mwn[r] = mrow[r][ktn];
    }

    // ---- S = Q K^T
    f32x4 sacc[2];
#pragma unroll
    for (int nf = 0; nf < 2; ++nf) sacc[nf] = zero4;
#pragma unroll
    for (int c = 0; c < 8; ++c) {
#pragma unroll
      for (int nf = 0; nf < 2; ++nf) {
        int n = nf * 16 + l15;
        s16x8 kb = *(const s16x8*)&Ks[n * 256 + (((quad + 4 * c) ^ (n & 7)) << 3)];
        sacc[nf] = mfma_bf16(qa[c], kb, sacc[nf]);
      }
    }

    // ---- no-max softmax
    float pvv[2][4];
#pragma unroll
    for (int r = 0; r < 4; ++r) {
      unsigned int bits = mw[r] >> l15;
#pragma unroll
      for (int nf = 0; nf < 2; ++nf) {
        float p = ((bits >> (nf * 16)) & 1u) ? 0.f : EXP2F(sacc[nf][r] * L2E);
        pvv[nf][r] = p;
        l_r[r] += p;
      }
    }

    // ---- P -> LDS (wave-private)
#pragma unroll
    for (int nf = 0; nf < 2; ++nf)
#pragma unroll
      for (int r = 0; r < 4; ++r) {
        int key = nf * 16 + l15;
        int ql = quad * 4 + r;
        Ps[w * 640 + ql * 40 + key] = f2bf(pvv[nf][r]);
      }

    // ---- O^T += V^T P^T
    {
      s16x8 bp = *(const s16x8*)&Ps[w * 640 + l15 * 40 + quad * 8];
#pragma unroll
      for (int mf = 0; mf < 16; ++mf) {
        int d = mf * 16 + l15;
        s16x8 av = *(const s16x8*)&Vs[d * 32 + ((quad ^ (d & 3)) << 3)];
        acc[mf] = mfma_bf16(av, bp, acc[mf]);
      }
    }

#pragma unroll
    for (int r = 0; r < 4; ++r) mw[r] = mwn[r];
  }

  // ---- deferred row-sum reduction
#pragma unroll
  for (int r = 0; r < 4; ++r) {
#pragma unroll
    for (int d = 1; d < 16; d <<= 1) l_r[r] += __shfl_xor(l_r[r], d, 64);
  }

  if (gridDim.z == 1) {
    float l4[4];
    int srcl = (l15 >> 2) << 4;
#pragma unroll
    for (int r = 0; r < 4; ++r) l4[r] = __shfl(l_r[r], srcl, 64);
    float lq = sel4(l4, l15 & 3);
    float linv = (lq > 0.f) ? (1.0f / lq) : 0.f;
    float* op = out + ((size_t)b * S_ + q0 + w * 16 + l15) * H_ + quad * 4;
#pragma unroll
    for (int mf = 0; mf < 16; ++mf) {
      float4 o;
      o.x = acc[mf][0] * linv; o.y = acc[mf][1] * linv;
      o.z = acc[mf][2] * linv; o.w = acc[mf][3] * linv;
      *(float4*)(op + mf * 16) = o;
    }
  } else {
    int qg = q0 + w * 16 + l15;
    unsigned short* op =
        Op + (((size_t)split * B_ + b) * S_ + qg) * H_ + quad * 4;
#pragma unroll
    for (int mf = 0; mf < 16; ++mf) {
      u16x4 pk;
      pk[0] = f2bf(acc[mf][0]); pk[1] = f2bf(acc[mf][1]);
      pk[2] = f2bf(acc[mf][2]); pk[3] = f2bf(acc[mf][3]);
      *(u16x4*)(op + mf * 16) = pk;
    }
    if (l15 == 0) {
#pragma unroll
      for (int r = 0; r < 4; ++r) {
        int qr = q0 + w * 16 + quad * 4 + r;
        Ml[((size_t)split * B_ + b) * S_ + qr] = l_r[r];
      }
    }
  }
}

// ---------------------------------------------------------------------------
// Kernel 3: combine — out = sum_i O_i / sum_i l_i. grid (512,8) x 1024.
// ---------------------------------------------------------------------------
__global__ __launch_bounds__(1024) void combine_kernel(
    const unsigned short* __restrict__ Op, const float* __restrict__ Ml,
    float* __restrict__ out, int nsplit) {
  int q = blockIdx.x * 4 + (threadIdx.x >> 8);
  int b = blockIdx.y, d = threadIdx.x & 255;
  float osum = 0.f, lsum = 0.f;
  for (int i = 0; i < nsplit; ++i) {
    size_t ro = ((size_t)i * B_ + b) * S_ + q;
    lsum += Ml[ro];
    osum += bf2f(Op[ro * H_ + d]);
  }
  float linv = (lsum > 0.f) ? (1.0f / lsum) : 0.f;
  out[((size_t)b * S_ + q) * H_ + d] = osum * linv;
}

// ---------------------------------------------------------------------------
extern "C" void kernel_launch(void* const* d_in, const int* in_sizes, int n_in,
                              void* d_out, int out_size, void* d_ws, size_t ws_size,
                              hipStream_t stream) {
  const float* k_in = (const float*)d_in[0];
  const float* q_in = (const float*)d_in[1];
  const float* v_in = (const float*)d_in[2];
  const int* mask = (const int*)d_in[3];
  const float* Wq = (const float*)d_in[4];
  const float* Wk = (const float*)d_in[5];
  const float* Wv = (const float*)d_in[6];
  float* out = (float*)d_out;

  // ws (u16 units): Qb|Kb|Vt 3x4194304 | Wt 196608 | Mb 2097152 |
  // Op 4x4194304 | Ml 65536 f32  => 63,569,920 bytes
  unsigned short* Qb = (unsigned short*)d_ws;
  unsigned short* Kb = Qb + (size_t)4194304;
  unsigned short* Vt = Kb + (size_t)4194304;
  unsigned short* Wt = Vt + (size_t)4194304;
  unsigned short* Mb = Wt + (size_t)196608;
  unsigned short* Op = Mb + (size_t)2097152;
  float* Ml = (float*)(Op + (size_t)16777216);
  const size_t need = 63569920;
  int nsplit = (ws_size >= need) ? 4 : 1;

  hipLaunchKernelGGL(wt_kernel, dim3(48), dim3(256), 0, stream,
                     Wq, Wk, Wv, Wt);
  hipLaunchKernelGGL(fused_kernel, dim3(8960), dim3(256), 0, stream,
                     mask, Mb, q_in, k_in, v_in, Wt, Qb, Kb, Vt);
  hipLaunchKernelGGL(attn_kernel, dim3(8, 32, nsplit), dim3(256), 0, stream,
                     Qb, Kb, Vt, (const unsigned int*)Mb, Op, Ml, out);
  if (nsplit > 1)
    hipLaunchKernelGGL(combine_kernel, dim3(512, 8), dim3(1024), 0, stream,
                       Op, Ml, out, nsplit);
}

// Round 11
// 313.827 us; speedup vs baseline: 1.5073x; 1.5073x over previous
//
#include <hip/hip_runtime.h>

// SimpleAttention: B=8, S=2048, H=256
// R11: attn reverted to R9 optimum (async dbuf, (256,2), nsplit=2, no-max
//      softmax) — R10's (256,4) reg-cap caused unified-file spill (VGPR=64,
//      FETCH 388MB). Repack rewritten: int4/lane coalesced + shfl_xor nibble
//      pack (4x fewer load instrs than ballot version).

#define B_ 8
#define S_ 2048
#define H_ 256

typedef __attribute__((ext_vector_type(8))) short s16x8;   // 8 bf16 MFMA A/B frag
typedef __attribute__((ext_vector_type(4))) float f32x4;   // MFMA C/D frag
typedef __attribute__((ext_vector_type(4))) unsigned short u16x4;
typedef __attribute__((ext_vector_type(8))) unsigned short u16x8;

#if __has_builtin(__builtin_amdgcn_exp2f)
#define EXP2F(x) __builtin_amdgcn_exp2f(x)
#else
#define EXP2F(x) exp2f(x)
#endif
#define L2E 1.4426950408889634f

__device__ __forceinline__ unsigned short f2bf(float f) {
  unsigned int u = __builtin_bit_cast(unsigned int, f);
  u += 0x7fffu + ((u >> 16) & 1u);   // RNE
  return (unsigned short)(u >> 16);
}
__device__ __forceinline__ float bf2f(unsigned short h) {
  unsigned int u = ((unsigned int)h) << 16;
  return __builtin_bit_cast(float, u);
}
__device__ __forceinline__ f32x4 mfma_bf16(s16x8 a, s16x8 b, f32x4 c) {
  return __builtin_amdgcn_mfma_f32_16x16x32_bf16(a, b, c, 0, 0, 0);
}
__device__ __forceinline__ float sel4(const float v[4], int r) {
  float t0 = (r & 1) ? v[1] : v[0];
  float t1 = (r & 1) ? v[3] : v[2];
  return (r & 2) ? t1 : t0;
}
// async global->LDS, 16B/lane; LDS dest = wave-uniform base + lane*16
__device__ __forceinline__ void async16(const unsigned short* g, unsigned short* l) {
  __builtin_amdgcn_global_load_lds(
      (const __attribute__((address_space(1))) unsigned int*)g,
      (__attribute__((address_space(3))) unsigned int*)l, 16, 0, 0);
}

// ---------------------------------------------------------------------------
// Kernel 0: W[h][n] fp32 -> Wt[n][h] bf16. grid (48).
// ---------------------------------------------------------------------------
__global__ __launch_bounds__(256) void wt_kernel(
    const float* __restrict__ Wq, const float* __restrict__ Wk,
    const float* __restrict__ Wv, unsigned short* __restrict__ Wt) {
  __shared__ unsigned short tile[64 * 72];
  int z = blockIdx.x >> 4, x = blockIdx.x & 15;
  const float* W = (z == 0) ? Wq : (z == 1) ? Wk : Wv;
  int n0 = (x & 3) * 64, h0 = (x >> 2) * 64;
  int t = threadIdx.x;
#pragma unroll
  for (int j = 0; j < 4; ++j) {
    int c = j * 256 + t;
    int i = c >> 4, ch = c & 15;
    float4 f = *(const float4*)&W[(h0 + i) * 256 + n0 + ch * 4];
    u16x4 p;
    p[0] = f2bf(f.x); p[1] = f2bf(f.y); p[2] = f2bf(f.z); p[3] = f2bf(f.w);
    *(u16x4*)&tile[i * 72 + ch * 4] = p;
  }
  __syncthreads();
#pragma unroll
  for (int j = 0; j < 2; ++j) {
    int c = j * 256 + t;
    int nr = c >> 3, ch = c & 7;
    u16x8 o;
#pragma unroll
    for (int k = 0; k < 8; ++k) o[k] = tile[(ch * 8 + k) * 72 + nr];
    *(u16x8*)&Wt[z * 65536 + (n0 + nr) * 256 + h0 + ch * 8] = o;
  }
}

// ---------------------------------------------------------------------------
// Kernel 1: fused proj (blocks 0..767) + repack (blocks 768..2815).
// repack: lane loads int4 (wave = 1KB contiguous); nibble = 4 mask bits;
// two shfl_xor steps pack 4 lanes -> u16; lanes 0 mod 4 store (32B/wave).
// Block covers 16384 int32 (16 rounds x 1024).
// ---------------------------------------------------------------------------
__global__ __launch_bounds__(256) void fused_kernel(
    const int* __restrict__ mask, unsigned short* __restrict__ Mb,
    const float* __restrict__ Xq, const float* __restrict__ Xk,
    const float* __restrict__ Xv, const unsigned short* __restrict__ Wt,
    unsigned short* __restrict__ Qb, unsigned short* __restrict__ Kb,
    unsigned short* __restrict__ Vt) {
  __shared__ unsigned short plds[16384];        // 32KB (proj path only)

  int t = threadIdx.x;
  int w = t >> 6, lane = t & 63, quad = lane >> 4, l15 = lane & 15;

  if (blockIdx.x >= 768) {
    // ---- repack path
    size_t base = (size_t)(blockIdx.x - 768) * 16384;   // element index
    size_t wbase = base >> 4;                           // u16 word index
#pragma unroll 4
    for (int s = 0; s < 16; ++s) {
      int4 x = *(const int4*)&mask[base + s * 1024 + t * 4];
      int nib = (x.x != 0 ? 1 : 0) | (x.y != 0 ? 2 : 0) |
                (x.z != 0 ? 4 : 0) | (x.w != 0 ? 8 : 0);
      int m8 = nib | (__shfl_xor(nib, 1, 64) << 4);     // valid on even lanes
      int v16 = m8 | (__shfl_xor(m8, 2, 64) << 8);      // valid on lane%4==0
      if ((lane & 3) == 0)
        Mb[wbase + s * 64 + w * 16 + (lane >> 2)] = (unsigned short)v16;
    }
    return;
  }

  // ---- proj path (R8/R9 structure)
  int z = blockIdx.x >> 8;                      // 0..2
  int bx = blockIdx.x & 255;
  const float* X = (z == 0) ? Xq : (z == 1) ? Xk : Xv;
  const unsigned short* Wz = Wt + z * 65536;

  int m0 = bx * 64;
  const float* xrow = X + (size_t)(m0 + w * 16 + l15) * H_;

  f32x4 zero4 = {0.f, 0.f, 0.f, 0.f};
  f32x4 acc[16];
#pragma unroll
  for (int i = 0; i < 16; ++i) acc[i] = zero4;

#pragma unroll
  for (int j = 0; j < 4; ++j) {
    int c = j * 256 + t;
    int n = c >> 2, p = c & 3;
    async16(Wz + n * 256 + ((p ^ ((n >> 1) & 3)) << 3),
            plds + j * 2048 + w * 512);
  }
  float4 a0 = *(const float4*)(xrow + quad * 8);
  float4 a1 = *(const float4*)(xrow + quad * 8 + 4);

  for (int c8 = 0; c8 < 8; ++c8) {
    int cur = c8 & 1;
    unsigned short* Wc = plds + cur * 8192;
    __syncthreads();   // drains buf[cur] asyncs; buf[cur^1] free

    if (c8 < 7) {
      unsigned short* Wn = plds + (cur ^ 1) * 8192;
#pragma unroll
      for (int j = 0; j < 4; ++j) {
        int c = j * 256 + t;
        int n = c >> 2, p = c & 3;
        async16(Wz + n * 256 + (c8 + 1) * 32 + ((p ^ ((n >> 1) & 3)) << 3),
                Wn + j * 2048 + w * 512);
      }
    }
    float4 na0, na1;
    if (c8 < 7) {
      na0 = *(const float4*)(xrow + (c8 + 1) * 32 + quad * 8);
      na1 = *(const float4*)(xrow + (c8 + 1) * 32 + quad * 8 + 4);
    }
    s16x8 af;
    af[0] = (short)f2bf(a0.x); af[1] = (short)f2bf(a0.y);
    af[2] = (short)f2bf(a0.z); af[3] = (short)f2bf(a0.w);
    af[4] = (short)f2bf(a1.x); af[5] = (short)f2bf(a1.y);
    af[6] = (short)f2bf(a1.z); af[7] = (short)f2bf(a1.w);

#pragma unroll
    for (int nf = 0; nf < 16; ++nf) {
      int n = nf * 16 + l15;
      s16x8 bf = *(const s16x8*)&Wc[n * 32 + ((quad ^ ((n >> 1) & 3)) << 3)];
      acc[nf] = mfma_bf16(af, bf, acc[nf]);
    }
    a0 = na0; a1 = na1;
  }
  __syncthreads();   // W bufs free; epilogue tile aliases

  float scale = (z == 0) ? 0.0625f : 1.0f;
  int b = m0 >> 11, s0 = m0 & 2047;
#pragma unroll
  for (int h = 0; h < 2; ++h) {
    if (h) __syncthreads();
    if (z < 2) {
#pragma unroll
      for (int nf2 = 0; nf2 < 8; ++nf2) {
        int n = nf2 * 16 + l15;
#pragma unroll
        for (int r = 0; r < 4; ++r)
          plds[(w * 16 + quad * 4 + r) * 136 + n] = f2bf(acc[h * 8 + nf2][r] * scale);
      }
      __syncthreads();
      unsigned short* Y = (z == 0) ? Qb : Kb;
#pragma unroll
      for (int j = 0; j < 4; ++j) {
        int c = j * 256 + t;
        int mr = c >> 4, ch = c & 15;
        u16x8 o = *(const u16x8*)&plds[mr * 136 + ch * 8];
        *(u16x8*)&Y[(size_t)(m0 + mr) * H_ + h * 128 + ch * 8] = o;
      }
    } else {
#pragma unroll
      for (int nf2 = 0; nf2 < 8; ++nf2) {
        int dl = nf2 * 16 + l15;
#pragma unroll
        for (int r = 0; r < 4; ++r)
          plds[dl * 72 + (w * 16 + quad * 4 + r)] = f2bf(acc[h * 8 + nf2][r]);
      }
      __syncthreads();
#pragma unroll
      for (int j = 0; j < 4; ++j) {
        int c = j * 256 + t;                 // 0..1023
        int dr = c >> 3, ch = c & 7;         // d row 0..127, 8-s chunk
        u16x8 o = *(const u16x8*)&plds[dr * 72 + ch * 8];
        *(u16x8*)&Vt[((size_t)b * H_ + h * 128 + dr) * S_ + s0 + ch * 8] = o;
      }
    }
  }
}

// ---------------------------------------------------------------------------
// Kernel 2: flash attention (R9 optimum): no-max softmax, async dbuf,
// ONE barrier/iter, grid (8, 32, nsplit=2), (256,2). LDS 69KB.
// ---------------------------------------------------------------------------
__global__ __launch_bounds__(256, 2) void attn_kernel(
    const unsigned short* __restrict__ Qb, const unsigned short* __restrict__ Kb,
    const unsigned short* __restrict__ Vt, const unsigned int* __restrict__ Mb,
    unsigned short* __restrict__ Op, float* __restrict__ Ml,
    float* __restrict__ out) {
  __shared__ unsigned short lds[35328];   // 2*16384 + 1280 u16
  unsigned short* Ps = lds + 32768;       // [wave][16 q][40]

  int t = threadIdx.x;
  int w = t >> 6, lane = t & 63, quad = lane >> 4, l15 = lane & 15;
  int b = blockIdx.x;                     // batch -> XCD affinity
  int q0 = blockIdx.y * 64;
  int split = blockIdx.z, nsplit = gridDim.z;
  int kbeg = (64 * split) / nsplit, kend = (64 * (split + 1)) / nsplit;

  s16x8 qa[8];
  {
    const unsigned short* qp =
        Qb + ((size_t)b * S_ + q0 + w * 16 + l15) * H_ + quad * 8;
#pragma unroll
    for (int c = 0; c < 8; ++c) qa[c] = *(const s16x8*)(qp + 32 * c);
  }

  const unsigned short* Kbb = Kb + (size_t)b * S_ * H_;
  const unsigned short* Vbb = Vt + (size_t)b * H_ * S_;

  int krow = lane >> 5, kch = lane & 31;
  int vrow = lane >> 2, vch = lane & 3;

  f32x4 zero4 = {0.f, 0.f, 0.f, 0.f};
  f32x4 acc[16];
#pragma unroll
  for (int i = 0; i < 16; ++i) acc[i] = zero4;
  float l_r[4] = {0.f, 0.f, 0.f, 0.f};

  const unsigned int* mrow[4];
#pragma unroll
  for (int r = 0; r < 4; ++r)
    mrow[r] = Mb + ((size_t)b * S_ + q0 + w * 16 + quad * 4 + r) * 64;

  {
    int k0 = kbeg * 32;
    unsigned short* Kd = lds;
    unsigned short* Vd = lds + 8192;
#pragma unroll
    for (int j = 0; j < 4; ++j) {
      int key = (w * 4 + j) * 2 + krow;
      async16(Kbb + ((size_t)(k0 + key) << 8) + ((kch ^ (key & 7)) << 3),
              Kd + (w * 4 + j) * 512);
      int d = w * 64 + j * 16 + vrow;
      async16(Vbb + ((size_t)d << 11) + k0 + ((vch ^ (d & 3)) << 3),
              Vd + (w * 64 + j * 16) * 32);
    }
  }
  unsigned int mw[4];
#pragma unroll
  for (int r = 0; r < 4; ++r) mw[r] = mrow[r][kbeg];

  for (int kt = kbeg; kt < kend; ++kt) {
    int cur = (kt - kbeg) & 1;
    unsigned short* Ksc = lds + cur * 16384;
    unsigned short* Vsc = Ksc + 8192;
    __syncthreads();   // drains buf[cur] asyncs; buf[cur^1] free

    if (kt + 1 < kend) {
      int k0 = (kt + 1) * 32;
      unsigned short* Kd = lds + (cur ^ 1) * 16384;
      unsigned short* Vd = Kd + 8192;
#pragma unroll
      for (int j = 0; j < 4; ++j) {
        int key = (w * 4 + j) * 2 + krow;
        async16(Kbb + ((size_t)(k0 + key) << 8) + ((kch ^ (key & 7)) << 3),
                Kd + (w * 4 + j) * 512);
        int d = w * 64 + j * 16 + vrow;
        async16(Vbb + ((size_t)d << 11) + k0 + ((vch ^ (d & 3)) << 3),
                Vd + (w * 64 + j * 16) * 32);
      }
    }
    unsigned int mwn[4];
    {
      int ktn = (kt + 1 < kend) ? kt + 1 : kt;
#pragma unroll
      for (int r = 0; r < 4; ++r) mwn[r] = mrow[r][ktn];
    }

    // ---- S = Q K^T
    f32x4 sacc[2];
#pragma unroll
    for (int nf = 0; nf < 2; ++nf) sacc[nf] = zero4;
#pragma unroll
    for (int c = 0; c < 8; ++c) {
#pragma unroll
      for (int nf = 0; nf < 2; ++nf) {
        int n = nf * 16 + l15;
        s16x8 kb = *(const s16x8*)&Ksc[n * 256 + (((quad + 4 * c) ^ (n & 7)) << 3)];
        sacc[nf] = mfma_bf16(qa[c], kb, sacc[nf]);
      }
    }

    // ---- no-max softmax: p = masked ? 0 : exp(s); partial row sums
    float pvv[2][4];
#pragma unroll
    for (int r = 0; r < 4; ++r) {
      unsigned int bits = mw[r] >> l15;
#pragma unroll
      for (int nf = 0; nf < 2; ++nf) {
        float p = ((bits >> (nf * 16)) & 1u) ? 0.f : EXP2F(sacc[nf][r] * L2E);
        pvv[nf][r] = p;
        l_r[r] += p;
      }
    }

    // ---- P -> LDS (wave-private)
#pragma unroll
    for (int nf = 0; nf < 2; ++nf)
#pragma unroll
      for (int r = 0; r < 4; ++r) {
        int key = nf * 16 + l15;
        int ql = quad * 4 + r;
        Ps[w * 640 + ql * 40 + key] = f2bf(pvv[nf][r]);
      }

    // ---- O^T += V^T P^T
    {
      s16x8 bp = *(const s16x8*)&Ps[w * 640 + l15 * 40 + quad * 8];
#pragma unroll
      for (int mf = 0; mf < 16; ++mf) {
        int d = mf * 16 + l15;
        s16x8 av = *(const s16x8*)&Vsc[d * 32 + ((quad ^ (d & 3)) << 3)];
        acc[mf] = mfma_bf16(av, bp, acc[mf]);
      }
    }

#pragma unroll
    for (int r = 0; r < 4; ++r) mw[r] = mwn[r];
  }

  // ---- deferred row-sum reduction
#pragma unroll
  for (int r = 0; r < 4; ++r) {
#pragma unroll
    for (int d = 1; d < 16; d <<= 1) l_r[r] += __shfl_xor(l_r[r], d, 64);
  }

  if (gridDim.z == 1) {
    float l4[4];
    int srcl = (l15 >> 2) << 4;
#pragma unroll
    for (int r = 0; r < 4; ++r) l4[r] = __shfl(l_r[r], srcl, 64);
    float lq = sel4(l4, l15 & 3);
    float linv = (lq > 0.f) ? (1.0f / lq) : 0.f;
    float* op = out + ((size_t)b * S_ + q0 + w * 16 + l15) * H_ + quad * 4;
#pragma unroll
    for (int mf = 0; mf < 16; ++mf) {
      float4 o;
      o.x = acc[mf][0] * linv; o.y = acc[mf][1] * linv;
      o.z = acc[mf][2] * linv; o.w = acc[mf][3] * linv;
      *(float4*)(op + mf * 16) = o;
    }
  } else {
    int qg = q0 + w * 16 + l15;
    unsigned short* op =
        Op + (((size_t)split * B_ + b) * S_ + qg) * H_ + quad * 4;
#pragma unroll
    for (int mf = 0; mf < 16; ++mf) {
      u16x4 pk;
      pk[0] = f2bf(acc[mf][0]); pk[1] = f2bf(acc[mf][1]);
      pk[2] = f2bf(acc[mf][2]); pk[3] = f2bf(acc[mf][3]);
      *(u16x4*)(op + mf * 16) = pk;
    }
    if (l15 == 0) {
#pragma unroll
      for (int r = 0; r < 4; ++r) {
        int qr = q0 + w * 16 + quad * 4 + r;
        Ml[((size_t)split * B_ + b) * S_ + qr] = l_r[r];
      }
    }
  }
}

// ---------------------------------------------------------------------------
// Kernel 3: combine — out = sum_i O_i / sum_i l_i. grid (512,8) x 1024.
// ---------------------------------------------------------------------------
__global__ __launch_bounds__(1024) void combine_kernel(
    const unsigned short* __restrict__ Op, const float* __restrict__ Ml,
    float* __restrict__ out, int nsplit) {
  int q = blockIdx.x * 4 + (threadIdx.x >> 8);
  int b = blockIdx.y, d = threadIdx.x & 255;
  float osum = 0.f, lsum = 0.f;
  for (int i = 0; i < nsplit; ++i) {
    size_t ro = ((size_t)i * B_ + b) * S_ + q;
    lsum += Ml[ro];
    osum += bf2f(Op[ro * H_ + d]);
  }
  float linv = (lsum > 0.f) ? (1.0f / lsum) : 0.f;
  out[((size_t)b * S_ + q) * H_ + d] = osum * linv;
}

// ---------------------------------------------------------------------------
extern "C" void kernel_launch(void* const* d_in, const int* in_sizes, int n_in,
                              void* d_out, int out_size, void* d_ws, size_t ws_size,
                              hipStream_t stream) {
  const float* k_in = (const float*)d_in[0];
  const float* q_in = (const float*)d_in[1];
  const float* v_in = (const float*)d_in[2];
  const int* mask = (const int*)d_in[3];
  const float* Wq = (const float*)d_in[4];
  const float* Wk = (const float*)d_in[5];
  const float* Wv = (const float*)d_in[6];
  float* out = (float*)d_out;

  unsigned short* Qb = (unsigned short*)d_ws;
  unsigned short* Kb = Qb + (size_t)4194304;
  unsigned short* Vt = Kb + (size_t)4194304;
  unsigned short* Wt = Vt + (size_t)4194304;
  unsigned short* Mb = Wt + (size_t)196608;
  unsigned short* Op = Mb + (size_t)2097152;
  float* Ml = (float*)(Op + (size_t)8388608);
  const size_t need = 46792704;
  int nsplit = (ws_size >= need) ? 2 : 1;

  hipLaunchKernelGGL(wt_kernel, dim3(48), dim3(256), 0, stream,
                     Wq, Wk, Wv, Wt);
  hipLaunchKernelGGL(fused_kernel, dim3(2816), dim3(256), 0, stream,
                     mask, Mb, q_in, k_in, v_in, Wt, Qb, Kb, Vt);
  hipLaunchKernelGGL(attn_kernel, dim3(8, 32, nsplit), dim3(256), 0, stream,
                     Qb, Kb, Vt, (const unsigned int*)Mb, Op, Ml, out);
  if (nsplit > 1)
    hipLaunchKernelGGL(combine_kernel, dim3(512, 8), dim3(1024), 0, stream,
                       Op, Ml, out, nsplit);
}